// Round 2
// baseline (115.916 us; speedup 1.0000x reference)
//
#include <hip/hip_runtime.h>
#include <hip/hip_bf16.h>
#include <cmath>

typedef unsigned short u16;
typedef __attribute__((ext_vector_type(8))) short short8v;
typedef __attribute__((ext_vector_type(8))) unsigned short ushort8v;
typedef __attribute__((ext_vector_type(4))) float f32x4;

#define NPIX 784      // 28*28
#define KP   800      // padded K (25 k-frags of 32)
#define NH   800      // HID
#define NROWS 32768

__device__ __forceinline__ u16 f2bf(float f) {
    union { float f; unsigned int u; } v; v.f = f;
    unsigned int u = v.u;
    unsigned int r = (u + 0x7FFFu + ((u >> 16) & 1u)) >> 16;   // RNE
    return (u16)r;
}

// ---------------------------------------------------------------------------
// Kernel 1: kre = Re(ifft2(ifftshift(tmask))), separable 28-pt DFT, 1 block.
// Also sets flag = 1.0 if kre is (numerically) a delta -> conv is identity.
// ---------------------------------------------------------------------------
__global__ void k_kre(const float* __restrict__ MRE, const float* __restrict__ MIM,
                      float* __restrict__ KRE, float* __restrict__ FLAG)
{
    __shared__ float msre[784], msim[784], tre[784], tim[784];
    __shared__ float c28[28], s28[28];
    __shared__ int smax;

    const int t = threadIdx.x;   // blockDim = 832
    if (t < 28) {
        float th = (float)t * (6.283185307179586f / 28.0f);
        s28[t] = sinf(th);
        c28[t] = cosf(th);
    }
    if (t == 0) smax = 0;
    if (t < 784) {
        int r = t / 28, c = t - r * 28;
        int idx = ((r + 14) % 28) * 28 + ((c + 14) % 28);   // ifftshift
        msre[t] = MRE[idx];
        msim[t] = MIM[idx];
    }
    __syncthreads();
    if (t < 784) {
        int u = t / 28, cc = t - u * 28;
        float re = 0.f, im = 0.f;
        int ph = 0;
        for (int v = 0; v < 28; ++v) {
            float cr = c28[ph], ci = s28[ph];
            float ar = msre[u * 28 + v], ai = msim[u * 28 + v];
            re += ar * cr - ai * ci;
            im += ar * ci + ai * cr;
            ph += cc; if (ph >= 28) ph -= 28;
        }
        tre[t] = re; tim[t] = im;
    }
    __syncthreads();
    float dev = 0.f;
    if (t < 784) {
        int pr = t / 28, pc = t - pr * 28;
        float s = 0.f;
        int ph = 0;
        for (int u = 0; u < 28; ++u) {
            s += tre[u * 28 + pc] * c28[ph] - tim[u * 28 + pc] * s28[ph];
            ph += pr; if (ph >= 28) ph -= 28;
        }
        s *= (1.0f / 784.0f);
        KRE[t] = s;
        dev = fabsf(s - (t == 0 ? 1.0f : 0.0f));
    }
    #pragma unroll
    for (int m = 32; m >= 1; m >>= 1) dev = fmaxf(dev, __shfl_xor(dev, m, 64));
    if ((t & 63) == 0) atomicMax(&smax, __float_as_int(dev));
    __syncthreads();
    if (t == 0) FLAG[0] = (__int_as_float(smax) < 1e-4f) ? 1.0f : 0.0f;
}

// ---------------------------------------------------------------------------
// Kernel 2: w1_eff[c][k] packed into MFMA B-fragment order, bf16.
// ---------------------------------------------------------------------------
__global__ void k_w1pack(const float* __restrict__ W1, const float* __restrict__ KRE,
                         const float* __restrict__ FLAG, u16* __restrict__ W1P)
{
    const int c = blockIdx.x;    // 0..799
    const int t = threadIdx.x;   // 128
    const bool delta = (FLAG[0] > 0.5f);
    __shared__ float w1d[56 * 56];
    __shared__ float kr[784];

    if (delta) {
        if (t < 100) {
            int k0 = t * 8;
            ushort8v h;
            if (k0 + 7 < NPIX) {
                const float4* wp = (const float4*)(W1 + (size_t)c * NPIX + k0);
                float4 a = wp[0], b = wp[1];
                h[0] = f2bf(a.x); h[1] = f2bf(a.y); h[2] = f2bf(a.z); h[3] = f2bf(a.w);
                h[4] = f2bf(b.x); h[5] = f2bf(b.y); h[6] = f2bf(b.z); h[7] = f2bf(b.w);
            } else {
                #pragma unroll
                for (int e = 0; e < 8; ++e) {
                    int k = k0 + e;
                    h[e] = (k < NPIX) ? f2bf(W1[(size_t)c * NPIX + k]) : (u16)0;
                }
            }
            int kf = k0 >> 5, r = k0 & 31;
            int l  = ((r >> 3) << 4) | (c & 15);
            int nf = c >> 4;
            ((ushort8v*)W1P)[(nf * 25 + kf) * 64 + l] = h;
        }
        return;
    }
    for (int i = t; i < 784; i += 128) kr[i] = KRE[i];
    for (int i = t; i < 3136; i += 128) {
        int r = i / 56, cc = i - r * 56;
        w1d[i] = W1[(size_t)c * NPIX + (r % 28) * 28 + (cc % 28)];
    }
    __syncthreads();
    for (int k = t; k < KP; k += 128) {
        float v = 0.f;
        if (k < NPIX) {
            int krr = k / 28, kcc = k - krr * 28;
            for (int dr = 0; dr < 28; ++dr) {
                const float* wrow = &w1d[(krr + dr) * 56 + kcc];
                const float* krow = &kr[dr * 28];
                #pragma unroll 4
                for (int dc = 0; dc < 28; ++dc) v += wrow[dc] * krow[dc];
            }
        }
        int kf = k >> 5, r = k & 31;
        int l  = ((r >> 3) << 4) | (c & 15);
        int nf = c >> 4;
        W1P[(size_t)(((nf * 25 + kf) * 64 + l) << 3) | (r & 7)] = f2bf(v);
    }
}

// ---------------------------------------------------------------------------
// Kernel 3: fused GEMM1 + relu + GEMM2 + log_softmax.
// v2: T14 async-stage split (X loads issued early, convert+ds_write late),
//     1-deep B-frag register double-buffer across 25 flattened k-steps,
//     setprio around MFMA clusters, PL overlaid on As (LDS 68.6 -> 43 KB).
// ---------------------------------------------------------------------------
#define LDA 168          // padded LDS row stride (bf16 elems): 160 + 8
__global__ __launch_bounds__(640, 3) void k_main(
    const float* __restrict__ X, const u16* __restrict__ W1P,
    const float* __restrict__ B1, const float* __restrict__ W4,
    const float* __restrict__ B4, float* __restrict__ OUT)
{
    __shared__ __align__(16) char SMEM[2 * 64 * LDA * 2];   // 43008 B
    u16*   As = (u16*)SMEM;                 // As[buf*64*LDA + ...], live in main loop
    float* PL = (float*)SMEM;               // overlay: PL[(w*64+row)*10 + o], post-loop

    const int t = threadIdx.x;
    const int row0 = blockIdx.x * 64;
    const int l = t & 63, w = t >> 6;
    const int lc = l & 15, lk = l >> 4;
    const int srow = t / 10, slot = t - srow * 10;
    const float* xrow = X + (size_t)(row0 + srow) * NPIX;

    f32x4 acc[4][5];
    #pragma unroll
    for (int m = 0; m < 4; ++m)
        #pragma unroll
        for (int n = 0; n < 5; ++n) acc[m][n] = (f32x4)(0.0f);

    const short8v* BP = (const short8v*)W1P;
    short8v bb[2][5];

    // ---- prologue: stage 0 into As[0]; preload B frags for kt=0 ----
    {
        int k0 = slot * 16;
        const float4* p = (const float4*)(xrow + k0);
        float4 a = p[0], b = p[1], c = p[2], d = p[3];
        ushort8v h0, h1;
        h0[0]=f2bf(a.x); h0[1]=f2bf(a.y); h0[2]=f2bf(a.z); h0[3]=f2bf(a.w);
        h0[4]=f2bf(b.x); h0[5]=f2bf(b.y); h0[6]=f2bf(b.z); h0[7]=f2bf(b.w);
        h1[0]=f2bf(c.x); h1[1]=f2bf(c.y); h1[2]=f2bf(c.z); h1[3]=f2bf(c.w);
        h1[4]=f2bf(d.x); h1[5]=f2bf(d.y); h1[6]=f2bf(d.z); h1[7]=f2bf(d.w);
        u16* dst = As + srow * LDA + slot * 16;
        *(ushort8v*)dst = h0; *(ushort8v*)(dst + 8) = h1;
    }
    #pragma unroll
    for (int n = 0; n < 5; ++n)
        bb[0][n] = BP[((w * 5 + n) * 25 + 0) * 64 + l];
    __syncthreads();

    // ---- main loop: 5 stages x 5 kf, fully unrolled (compile-time parity) ----
    #pragma unroll
    for (int s = 0; s < 5; ++s) {
        const int buf = s & 1;
        // T14 issue-early: next stage's X -> registers (latency hides under MFMAs)
        float4 y0, y1, y2, y3;
        if (s < 4) {
            int k0 = (s + 1) * 160 + slot * 16;
            if (k0 < NPIX) {
                const float4* p = (const float4*)(xrow + k0);
                y0 = p[0]; y1 = p[1]; y2 = p[2]; y3 = p[3];
            } else {
                y0 = y1 = y2 = y3 = make_float4(0.f, 0.f, 0.f, 0.f);
            }
        }
        #pragma unroll
        for (int kf = 0; kf < 5; ++kf) {
            const int kt = s * 5 + kf;
            if (kt < 24) {   // 1-deep B prefetch for kt+1
                #pragma unroll
                for (int n = 0; n < 5; ++n)
                    bb[(kt + 1) & 1][n] = BP[((w * 5 + n) * 25 + (kt + 1)) * 64 + l];
            }
            const u16* abase = As + buf * (64 * LDA) + lc * LDA + lk * 8 + kf * 32;
            __builtin_amdgcn_s_setprio(1);
            #pragma unroll
            for (int m = 0; m < 4; ++m) {
                short8v a = *reinterpret_cast<const short8v*>(abase + m * (16 * LDA));
                #pragma unroll
                for (int n = 0; n < 5; ++n)
                    acc[m][n] = __builtin_amdgcn_mfma_f32_16x16x32_bf16(a, bb[kt & 1][n], acc[m][n], 0, 0, 0);
            }
            __builtin_amdgcn_s_setprio(0);
        }
        // T14 write-late: convert + ds_write after the MFMAs of this stage
        if (s < 4) {
            ushort8v h0, h1;
            h0[0]=f2bf(y0.x); h0[1]=f2bf(y0.y); h0[2]=f2bf(y0.z); h0[3]=f2bf(y0.w);
            h0[4]=f2bf(y1.x); h0[5]=f2bf(y1.y); h0[6]=f2bf(y1.z); h0[7]=f2bf(y1.w);
            h1[0]=f2bf(y2.x); h1[1]=f2bf(y2.y); h1[2]=f2bf(y2.z); h1[3]=f2bf(y2.w);
            h1[4]=f2bf(y3.x); h1[5]=f2bf(y3.y); h1[6]=f2bf(y3.z); h1[7]=f2bf(y3.w);
            u16* dst = As + (buf ^ 1) * (64 * LDA) + srow * LDA + slot * 16;
            *(ushort8v*)dst = h0; *(ushort8v*)(dst + 8) = h1;
        }
        __syncthreads();
    }

    // ---- epilogue: bias + relu ----
    #pragma unroll
    for (int n = 0; n < 5; ++n) {
        float bn = B1[w * 80 + n * 16 + lc];
        #pragma unroll
        for (int m = 0; m < 4; ++m)
            #pragma unroll
            for (int j = 0; j < 4; ++j)
                acc[m][n][j] = fmaxf(acc[m][n][j] + bn, 0.0f);
    }
    // ---- logits partials (reduce this wave's 80 cols) into PL overlay ----
    #pragma unroll
    for (int o = 0; o < 10; ++o) {
        float wv[5];
        #pragma unroll
        for (int n = 0; n < 5; ++n) wv[n] = W4[o * NH + w * 80 + n * 16 + lc];
        float p[4][4];
        #pragma unroll
        for (int m = 0; m < 4; ++m)
            #pragma unroll
            for (int j = 0; j < 4; ++j) {
                float s = acc[m][0][j] * wv[0];
                s += acc[m][1][j] * wv[1];
                s += acc[m][2][j] * wv[2];
                s += acc[m][3][j] * wv[3];
                s += acc[m][4][j] * wv[4];
                p[m][j] = s;
            }
        #pragma unroll
        for (int mask = 1; mask <= 8; mask <<= 1)
            #pragma unroll
            for (int m = 0; m < 4; ++m)
                #pragma unroll
                for (int j = 0; j < 4; ++j)
                    p[m][j] += __shfl_xor(p[m][j], mask, 64);
        if (lc == 0) {
            #pragma unroll
            for (int m = 0; m < 4; ++m)
                #pragma unroll
                for (int j = 0; j < 4; ++j)
                    PL[(w * 64 + (m * 16 + lk * 4 + j)) * 10 + o] = p[m][j];
        }
    }
    __syncthreads();
    // ---- cross-wave combine + log_softmax, one row per thread ----
    if (t < 64) {
        float lg[10];
        #pragma unroll
        for (int o = 0; o < 10; ++o) {
            float s = 0.f;
            #pragma unroll
            for (int w2 = 0; w2 < 10; ++w2) s += PL[(w2 * 64 + t) * 10 + o];
            lg[o] = s + B4[o];
        }
        float mx = lg[0];
        #pragma unroll
        for (int o = 1; o < 10; ++o) mx = fmaxf(mx, lg[o]);
        float se = 0.f;
        #pragma unroll
        for (int o = 0; o < 10; ++o) se += expf(lg[o] - mx);
        float lse = logf(se);
        float* op = OUT + (size_t)(row0 + t) * 10;
        #pragma unroll
        for (int o = 0; o < 10; ++o) op[o] = lg[o] - mx - lse;
    }
}

// ---------------------------------------------------------------------------
extern "C" void kernel_launch(void* const* d_in, const int* in_sizes, int n_in,
                              void* d_out, int out_size, void* d_ws, size_t ws_size,
                              hipStream_t stream)
{
    const float* X   = (const float*)d_in[0];
    const float* MRE = (const float*)d_in[1];
    const float* MIM = (const float*)d_in[2];
    const float* W1  = (const float*)d_in[3];
    const float* B1  = (const float*)d_in[4];
    const float* W4  = (const float*)d_in[5];
    const float* B4  = (const float*)d_in[6];
    float* OUT = (float*)d_out;

    float* kre  = (float*)d_ws;                       // 784 f32
    float* flag = kre + 784;                          // 1 f32
    u16*   w1p  = (u16*)((char*)d_ws + 4096);         // 50*25*64*8 bf16 = 1.28 MB

    k_kre<<<1, 832, 0, stream>>>(MRE, MIM, kre, flag);
    k_w1pack<<<800, 128, 0, stream>>>(W1, kre, flag, w1p);
    k_main<<<512, 640, 0, stream>>>(X, w1p, B1, W4, B4, OUT);
}

// Round 4
// 104.688 us; speedup vs baseline: 1.1072x; 1.1072x over previous
//
#include <hip/hip_runtime.h>
#include <hip/hip_bf16.h>
#include <cmath>

typedef unsigned short u16;
typedef __attribute__((ext_vector_type(8))) short short8v;
typedef __attribute__((ext_vector_type(4))) unsigned short ushort4v;
typedef __attribute__((ext_vector_type(8))) unsigned short ushort8v;
typedef __attribute__((ext_vector_type(4))) float f32x4;

#define NPIX 784      // 28*28
#define KP   800      // padded K (25 k-frags of 32)
#define NH   800      // HID
#define STRIDE 808    // LDS row stride, bf16 elems: 1616 B = 16*101 (16B-aligned rows,
                      // mod 128 = 80 -> rows hit all 8 bank-quads; b128 reads at floor)

__device__ __forceinline__ u16 f2bf(float f) {
    union { float f; unsigned int u; } v; v.f = f;
    unsigned int u = v.u;
    unsigned int r = (u + 0x7FFFu + ((u >> 16) & 1u)) >> 16;   // RNE
    return (u16)r;
}

// ---------------------------------------------------------------------------
// Kernel 1: kre = Re(ifft2(ifftshift(tmask))), separable 28-pt DFT, 1 block.
// Sets flag = 1.0 if kre is (numerically) a delta -> conv is identity.
// ---------------------------------------------------------------------------
__global__ void k_kre(const float* __restrict__ MRE, const float* __restrict__ MIM,
                      float* __restrict__ KRE, float* __restrict__ FLAG)
{
    __shared__ float msre[784], msim[784], tre[784], tim[784];
    __shared__ float c28[28], s28[28];
    __shared__ int smax;

    const int t = threadIdx.x;   // blockDim = 832
    if (t < 28) {
        float th = (float)t * (6.283185307179586f / 28.0f);
        s28[t] = sinf(th);
        c28[t] = cosf(th);
    }
    if (t == 0) smax = 0;
    if (t < 784) {
        int r = t / 28, c = t - r * 28;
        int idx = ((r + 14) % 28) * 28 + ((c + 14) % 28);   // ifftshift
        msre[t] = MRE[idx];
        msim[t] = MIM[idx];
    }
    __syncthreads();
    if (t < 784) {
        int u = t / 28, cc = t - u * 28;
        float re = 0.f, im = 0.f;
        int ph = 0;
        for (int v = 0; v < 28; ++v) {
            float cr = c28[ph], ci = s28[ph];
            float ar = msre[u * 28 + v], ai = msim[u * 28 + v];
            re += ar * cr - ai * ci;
            im += ar * ci + ai * cr;
            ph += cc; if (ph >= 28) ph -= 28;
        }
        tre[t] = re; tim[t] = im;
    }
    __syncthreads();
    float dev = 0.f;
    if (t < 784) {
        int pr = t / 28, pc = t - pr * 28;
        float s = 0.f;
        int ph = 0;
        for (int u = 0; u < 28; ++u) {
            s += tre[u * 28 + pc] * c28[ph] - tim[u * 28 + pc] * s28[ph];
            ph += pr; if (ph >= 28) ph -= 28;
        }
        s *= (1.0f / 784.0f);
        KRE[t] = s;
        dev = fabsf(s - (t == 0 ? 1.0f : 0.0f));
    }
    #pragma unroll
    for (int m = 32; m >= 1; m >>= 1) dev = fmaxf(dev, __shfl_xor(dev, m, 64));
    if ((t & 63) == 0) atomicMax(&smax, __float_as_int(dev));
    __syncthreads();
    if (t == 0) FLAG[0] = (__int_as_float(smax) < 1e-4f) ? 1.0f : 0.0f;
}

// ---------------------------------------------------------------------------
// Kernel 2: w1_eff[c][k] packed into MFMA B-fragment order, bf16.
// ---------------------------------------------------------------------------
__global__ void k_w1pack(const float* __restrict__ W1, const float* __restrict__ KRE,
                         const float* __restrict__ FLAG, u16* __restrict__ W1P)
{
    const int c = blockIdx.x;    // 0..799
    const int t = threadIdx.x;   // 128
    const bool delta = (FLAG[0] > 0.5f);
    __shared__ float w1d[56 * 56];
    __shared__ float kr[784];

    if (delta) {
        if (t < 100) {
            int k0 = t * 8;
            ushort8v h;
            if (k0 + 7 < NPIX) {
                const float4* wp = (const float4*)(W1 + (size_t)c * NPIX + k0);
                float4 a = wp[0], b = wp[1];
                h[0] = f2bf(a.x); h[1] = f2bf(a.y); h[2] = f2bf(a.z); h[3] = f2bf(a.w);
                h[4] = f2bf(b.x); h[5] = f2bf(b.y); h[6] = f2bf(b.z); h[7] = f2bf(b.w);
            } else {
                #pragma unroll
                for (int e = 0; e < 8; ++e) {
                    int k = k0 + e;
                    h[e] = (k < NPIX) ? f2bf(W1[(size_t)c * NPIX + k]) : (u16)0;
                }
            }
            int kf = k0 >> 5, r = k0 & 31;
            int l  = ((r >> 3) << 4) | (c & 15);
            int nf = c >> 4;
            ((ushort8v*)W1P)[(nf * 25 + kf) * 64 + l] = h;
        }
        return;
    }
    for (int i = t; i < 784; i += 128) kr[i] = KRE[i];
    for (int i = t; i < 3136; i += 128) {
        int r = i / 56, cc = i - r * 56;
        w1d[i] = W1[(size_t)c * NPIX + (r % 28) * 28 + (cc % 28)];
    }
    __syncthreads();
    for (int k = t; k < KP; k += 128) {
        float v = 0.f;
        if (k < NPIX) {
            int krr = k / 28, kcc = k - krr * 28;
            for (int dr = 0; dr < 28; ++dr) {
                const float* wrow = &w1d[(krr + dr) * 56 + kcc];
                const float* krow = &kr[dr * 28];
                #pragma unroll 4
                for (int dc = 0; dc < 28; ++dc) v += wrow[dc] * krow[dc];
            }
        }
        int kf = k >> 5, r = k & 31;
        int l  = ((r >> 3) << 4) | (c & 15);
        int nf = c >> 4;
        W1P[(size_t)(((nf * 25 + kf) * 64 + l) << 3) | (r & 7)] = f2bf(v);
    }
}

// ---------------------------------------------------------------------------
// Kernel 3: fused GEMM1 + relu + GEMM2 + log_softmax.
// v4: whole 64x800 bf16 tile in LDS (101 KB, 1 block/CU), ONE barrier before
//     the K loop -> waves free-run across all 25 kt steps. B-frag 1-deep reg
//     dbuf + setprio. amdgpu_waves_per_eu(3,3) forces the ~168-VGPR budget so
//     the prefetch regs don't spill (round-2 failure mode).
//     Stage: 20 quads/thread in 2 batches of 10 in-flight float4 loads.
// ---------------------------------------------------------------------------
__global__ __launch_bounds__(640) __attribute__((amdgpu_waves_per_eu(3, 3)))
void k_main(
    const float* __restrict__ X, const u16* __restrict__ W1P,
    const float* __restrict__ B1, const float* __restrict__ W4,
    const float* __restrict__ B4, float* __restrict__ OUT)
{
    __shared__ __align__(16) u16 As[64 * STRIDE];   // 103424 B
    float* PL = (float*)As;                          // overlay after GEMM1

    const int t = threadIdx.x;
    const int row0 = blockIdx.x * 64;
    const int l = t & 63, w = t >> 6;
    const int lc = l & 15, lk = l >> 4;

    // ---- stage whole tile: 64 rows x 200 quads (196 data + 4 zero-pad) ----
    // 12800 quads / 640 thr = 20 each, in 2 passes of 10 loads in flight.
    #pragma unroll
    for (int pass = 0; pass < 2; ++pass) {
        float4 y[10];
        #pragma unroll
        for (int i = 0; i < 10; ++i) {
            int idx = t + 640 * (pass * 10 + i);
            int row = idx / 200, q = idx - row * 200;
            if (q < 196)
                y[i] = *(const float4*)(X + (size_t)(row0 + row) * NPIX + (q << 2));
            else
                y[i] = make_float4(0.f, 0.f, 0.f, 0.f);
        }
        #pragma unroll
        for (int i = 0; i < 10; ++i) {
            int idx = t + 640 * (pass * 10 + i);
            int row = idx / 200, q = idx - row * 200;
            ushort4v h;
            h[0] = f2bf(y[i].x); h[1] = f2bf(y[i].y);
            h[2] = f2bf(y[i].z); h[3] = f2bf(y[i].w);
            *(ushort4v*)(As + row * STRIDE + (q << 2)) = h;
        }
    }

    f32x4 acc[4][5];
    #pragma unroll
    for (int m = 0; m < 4; ++m)
        #pragma unroll
        for (int n = 0; n < 5; ++n) acc[m][n] = (f32x4)(0.0f);

    const short8v* BP = (const short8v*)W1P;
    short8v bb[2][5];
    #pragma unroll
    for (int n = 0; n < 5; ++n)
        bb[0][n] = BP[((w * 5 + n) * 25 + 0) * 64 + l];

    __syncthreads();   // tile ready -- the ONLY pre-loop barrier

    // ---- 25 kt steps, fully unrolled, no barriers, 1-deep B prefetch ----
    #pragma unroll
    for (int kt = 0; kt < 25; ++kt) {
        if (kt < 24) {
            #pragma unroll
            for (int n = 0; n < 5; ++n)
                bb[(kt + 1) & 1][n] = BP[((w * 5 + n) * 25 + (kt + 1)) * 64 + l];
        }
        const u16* ab = As + lc * STRIDE + kt * 32 + lk * 8;
        __builtin_amdgcn_s_setprio(1);
        #pragma unroll
        for (int m = 0; m < 4; ++m) {
            short8v a = *(const short8v*)(ab + m * (16 * STRIDE));
            #pragma unroll
            for (int n = 0; n < 5; ++n)
                acc[m][n] = __builtin_amdgcn_mfma_f32_16x16x32_bf16(a, bb[kt & 1][n], acc[m][n], 0, 0, 0);
        }
        __builtin_amdgcn_s_setprio(0);
    }
    __syncthreads();   // all As reads done before PL overlay

    // ---- epilogue: bias + relu ----
    #pragma unroll
    for (int n = 0; n < 5; ++n) {
        float bn = B1[w * 80 + n * 16 + lc];
        #pragma unroll
        for (int m = 0; m < 4; ++m)
            #pragma unroll
            for (int j = 0; j < 4; ++j)
                acc[m][n][j] = fmaxf(acc[m][n][j] + bn, 0.0f);
    }
    // ---- logits partials (this wave's 80 cols) into PL overlay ----
    #pragma unroll
    for (int o = 0; o < 10; ++o) {
        float wv[5];
        #pragma unroll
        for (int n = 0; n < 5; ++n) wv[n] = W4[o * NH + w * 80 + n * 16 + lc];
        float p[4][4];
        #pragma unroll
        for (int m = 0; m < 4; ++m)
            #pragma unroll
            for (int j = 0; j < 4; ++j) {
                float s = acc[m][0][j] * wv[0];
                s += acc[m][1][j] * wv[1];
                s += acc[m][2][j] * wv[2];
                s += acc[m][3][j] * wv[3];
                s += acc[m][4][j] * wv[4];
                p[m][j] = s;
            }
        #pragma unroll
        for (int mask = 1; mask <= 8; mask <<= 1)
            #pragma unroll
            for (int m = 0; m < 4; ++m)
                #pragma unroll
                for (int j = 0; j < 4; ++j)
                    p[m][j] += __shfl_xor(p[m][j], mask, 64);
        if (lc == 0) {
            #pragma unroll
            for (int m = 0; m < 4; ++m)
                #pragma unroll
                for (int j = 0; j < 4; ++j)
                    PL[(w * 64 + (m * 16 + lk * 4 + j)) * 10 + o] = p[m][j];
        }
    }
    __syncthreads();
    // ---- cross-wave combine + log_softmax, one row per thread ----
    if (t < 64) {
        float lg[10];
        #pragma unroll
        for (int o = 0; o < 10; ++o) {
            float s = 0.f;
            #pragma unroll
            for (int w2 = 0; w2 < 10; ++w2) s += PL[(w2 * 64 + t) * 10 + o];
            lg[o] = s + B4[o];
        }
        float mx = lg[0];
        #pragma unroll
        for (int o = 1; o < 10; ++o) mx = fmaxf(mx, lg[o]);
        float se = 0.f;
        #pragma unroll
        for (int o = 0; o < 10; ++o) se += expf(lg[o] - mx);
        float lse = logf(se);
        float* op = OUT + (size_t)(row0 + t) * 10;
        #pragma unroll
        for (int o = 0; o < 10; ++o) op[o] = lg[o] - mx - lse;
    }
}

// ---------------------------------------------------------------------------
extern "C" void kernel_launch(void* const* d_in, const int* in_sizes, int n_in,
                              void* d_out, int out_size, void* d_ws, size_t ws_size,
                              hipStream_t stream)
{
    const float* X   = (const float*)d_in[0];
    const float* MRE = (const float*)d_in[1];
    const float* MIM = (const float*)d_in[2];
    const float* W1  = (const float*)d_in[3];
    const float* B1  = (const float*)d_in[4];
    const float* W4  = (const float*)d_in[5];
    const float* B4  = (const float*)d_in[6];
    float* OUT = (float*)d_out;

    float* kre  = (float*)d_ws;                       // 784 f32
    float* flag = kre + 784;                          // 1 f32
    u16*   w1p  = (u16*)((char*)d_ws + 4096);         // 50*25*64*8 bf16 = 1.28 MB

    k_kre<<<1, 832, 0, stream>>>(MRE, MIM, kre, flag);
    k_w1pack<<<800, 128, 0, stream>>>(W1, kre, flag, w1p);
    k_main<<<512, 640, 0, stream>>>(X, w1p, B1, W4, B4, OUT);
}

// Round 5
// 71.399 us; speedup vs baseline: 1.6235x; 1.4662x over previous
//
#include <hip/hip_runtime.h>
#include <hip/hip_bf16.h>
#include <cmath>

typedef unsigned short u16;
typedef __attribute__((ext_vector_type(8))) short short8v;
typedef __attribute__((ext_vector_type(4))) unsigned short ushort4v;
typedef __attribute__((ext_vector_type(8))) unsigned short ushort8v;
typedef __attribute__((ext_vector_type(4))) float f32x4;

#define NPIX 784      // 28*28
#define KP   800      // padded K (25 k-frags of 32)
#define NH   800      // HID
#define STRIDE 808    // LDS row stride, bf16 elems (1616 B rows, 16B-aligned)

__device__ __forceinline__ u16 f2bf(float f) {
    union { float f; unsigned int u; } v; v.f = f;
    unsigned int u = v.u;
    unsigned int r = (u + 0x7FFFu + ((u >> 16) & 1u)) >> 16;   // RNE
    return (u16)r;
}

// ---------------------------------------------------------------------------
// Kernel 1: kre = Re(ifft2(ifftshift(tmask))), separable 28-pt DFT, 1 block.
// Sets flag = 1.0 if kre is (numerically) a delta -> conv is identity.
// ---------------------------------------------------------------------------
__global__ void k_kre(const float* __restrict__ MRE, const float* __restrict__ MIM,
                      float* __restrict__ KRE, float* __restrict__ FLAG)
{
    __shared__ float msre[784], msim[784], tre[784], tim[784];
    __shared__ float c28[28], s28[28];
    __shared__ int smax;

    const int t = threadIdx.x;   // blockDim = 832
    if (t < 28) {
        float th = (float)t * (6.283185307179586f / 28.0f);
        s28[t] = sinf(th);
        c28[t] = cosf(th);
    }
    if (t == 0) smax = 0;
    if (t < 784) {
        int r = t / 28, c = t - r * 28;
        int idx = ((r + 14) % 28) * 28 + ((c + 14) % 28);   // ifftshift
        msre[t] = MRE[idx];
        msim[t] = MIM[idx];
    }
    __syncthreads();
    if (t < 784) {
        int u = t / 28, cc = t - u * 28;
        float re = 0.f, im = 0.f;
        int ph = 0;
        for (int v = 0; v < 28; ++v) {
            float cr = c28[ph], ci = s28[ph];
            float ar = msre[u * 28 + v], ai = msim[u * 28 + v];
            re += ar * cr - ai * ci;
            im += ar * ci + ai * cr;
            ph += cc; if (ph >= 28) ph -= 28;
        }
        tre[t] = re; tim[t] = im;
    }
    __syncthreads();
    float dev = 0.f;
    if (t < 784) {
        int pr = t / 28, pc = t - pr * 28;
        float s = 0.f;
        int ph = 0;
        for (int u = 0; u < 28; ++u) {
            s += tre[u * 28 + pc] * c28[ph] - tim[u * 28 + pc] * s28[ph];
            ph += pr; if (ph >= 28) ph -= 28;
        }
        s *= (1.0f / 784.0f);
        KRE[t] = s;
        dev = fabsf(s - (t == 0 ? 1.0f : 0.0f));
    }
    #pragma unroll
    for (int m = 32; m >= 1; m >>= 1) dev = fmaxf(dev, __shfl_xor(dev, m, 64));
    if ((t & 63) == 0) atomicMax(&smax, __float_as_int(dev));
    __syncthreads();
    if (t == 0) FLAG[0] = (__int_as_float(smax) < 1e-4f) ? 1.0f : 0.0f;
}

// ---------------------------------------------------------------------------
// Kernel 2: w1_eff[c][k] packed into MFMA B-fragment order, bf16.
// ---------------------------------------------------------------------------
__global__ void k_w1pack(const float* __restrict__ W1, const float* __restrict__ KRE,
                         const float* __restrict__ FLAG, u16* __restrict__ W1P)
{
    const int c = blockIdx.x;    // 0..799
    const int t = threadIdx.x;   // 128
    const bool delta = (FLAG[0] > 0.5f);
    __shared__ float w1d[56 * 56];
    __shared__ float kr[784];

    if (delta) {
        if (t < 100) {
            int k0 = t * 8;
            ushort8v h;
            if (k0 + 7 < NPIX) {
                const float4* wp = (const float4*)(W1 + (size_t)c * NPIX + k0);
                float4 a = wp[0], b = wp[1];
                h[0] = f2bf(a.x); h[1] = f2bf(a.y); h[2] = f2bf(a.z); h[3] = f2bf(a.w);
                h[4] = f2bf(b.x); h[5] = f2bf(b.y); h[6] = f2bf(b.z); h[7] = f2bf(b.w);
            } else {
                #pragma unroll
                for (int e = 0; e < 8; ++e) {
                    int k = k0 + e;
                    h[e] = (k < NPIX) ? f2bf(W1[(size_t)c * NPIX + k]) : (u16)0;
                }
            }
            int kf = k0 >> 5, r = k0 & 31;
            int l  = ((r >> 3) << 4) | (c & 15);
            int nf = c >> 4;
            ((ushort8v*)W1P)[(nf * 25 + kf) * 64 + l] = h;
        }
        return;
    }
    for (int i = t; i < 784; i += 128) kr[i] = KRE[i];
    for (int i = t; i < 3136; i += 128) {
        int r = i / 56, cc = i - r * 56;
        w1d[i] = W1[(size_t)c * NPIX + (r % 28) * 28 + (cc % 28)];
    }
    __syncthreads();
    for (int k = t; k < KP; k += 128) {
        float v = 0.f;
        if (k < NPIX) {
            int krr = k / 28, kcc = k - krr * 28;
            for (int dr = 0; dr < 28; ++dr) {
                const float* wrow = &w1d[(krr + dr) * 56 + kcc];
                const float* krow = &kr[dr * 28];
                #pragma unroll 4
                for (int dc = 0; dc < 28; ++dc) v += wrow[dc] * krow[dc];
            }
        }
        int kf = k >> 5, r = k & 31;
        int l  = ((r >> 3) << 4) | (c & 15);
        int nf = c >> 4;
        W1P[(size_t)(((nf * 25 + kf) * 64 + l) << 3) | (r & 7)] = f2bf(v);
    }
}

// ---------------------------------------------------------------------------
// Kernel 2b: pack W4 (10 x 800 f32) into B-fragment order, 16-col tile,
// cols 10..15 zero. W4P[(kt*64 + l)*8 + e] = W4[lc][kt*32 + lk*8 + e].
// ---------------------------------------------------------------------------
__global__ void k_w4pack(const float* __restrict__ W4, u16* __restrict__ W4P)
{
    int i = blockIdx.x * 256 + threadIdx.x;   // (kt*64 + l), 1600 total
    if (i >= 1600) return;
    int l = i & 63, kt = i >> 6;
    int lc = l & 15, lk = l >> 4;
    ushort8v h;
    #pragma unroll
    for (int e = 0; e < 8; ++e) {
        int k = kt * 32 + lk * 8 + e;
        h[e] = (lc < 10) ? f2bf(W4[lc * NH + k]) : (u16)0;
    }
    ((ushort8v*)W4P)[i] = h;
}

// ---------------------------------------------------------------------------
// Kernel 3: fused GEMM1 + relu + (MFMA) GEMM2 + log_softmax.
// v5: epilogue rebuilt — the 640-bpermute/lane shuffle reduction (the measured
//     binder: constant ~50 us across rounds 1/2/4) is replaced by:
//     h -> bf16 in-place over As, then GEMM2 via MFMA with k-steps split
//     across the 10 waves, partials combined through a 40 KB PL2 buffer.
// ---------------------------------------------------------------------------
__global__ __launch_bounds__(640) __attribute__((amdgpu_waves_per_eu(3, 3)))
void k_main(
    const float* __restrict__ X, const u16* __restrict__ W1P,
    const u16* __restrict__ W4P, const float* __restrict__ B1,
    const float* __restrict__ B4, float* __restrict__ OUT)
{
    __shared__ __align__(16) u16 As[64 * STRIDE];      // 103424 B: x tile, then h
    __shared__ __align__(16) float PL2[10 * 4 * 64 * 4]; // 40960 B: GEMM2 partials

    const int t = threadIdx.x;
    const int row0 = blockIdx.x * 64;
    const int l = t & 63, w = t >> 6;
    const int lc = l & 15, lk = l >> 4;

    // ---- stage whole tile: 64 rows x 200 quads (196 data + 4 zero-pad) ----
    #pragma unroll
    for (int pass = 0; pass < 2; ++pass) {
        float4 y[10];
        #pragma unroll
        for (int i = 0; i < 10; ++i) {
            int idx = t + 640 * (pass * 10 + i);
            int row = idx / 200, q = idx - row * 200;
            if (q < 196)
                y[i] = *(const float4*)(X + (size_t)(row0 + row) * NPIX + (q << 2));
            else
                y[i] = make_float4(0.f, 0.f, 0.f, 0.f);
        }
        #pragma unroll
        for (int i = 0; i < 10; ++i) {
            int idx = t + 640 * (pass * 10 + i);
            int row = idx / 200, q = idx - row * 200;
            ushort4v h;
            h[0] = f2bf(y[i].x); h[1] = f2bf(y[i].y);
            h[2] = f2bf(y[i].z); h[3] = f2bf(y[i].w);
            *(ushort4v*)(As + row * STRIDE + (q << 2)) = h;
        }
    }

    f32x4 acc[4][5];
    #pragma unroll
    for (int m = 0; m < 4; ++m)
        #pragma unroll
        for (int n = 0; n < 5; ++n) acc[m][n] = (f32x4)(0.0f);

    const short8v* BP = (const short8v*)W1P;
    short8v bb[2][5];
    #pragma unroll
    for (int n = 0; n < 5; ++n)
        bb[0][n] = BP[((w * 5 + n) * 25 + 0) * 64 + l];

    __syncthreads();   // tile ready

    // ---- GEMM1: 25 kt steps, no barriers, 1-deep B prefetch ----
    #pragma unroll
    for (int kt = 0; kt < 25; ++kt) {
        if (kt < 24) {
            #pragma unroll
            for (int n = 0; n < 5; ++n)
                bb[(kt + 1) & 1][n] = BP[((w * 5 + n) * 25 + (kt + 1)) * 64 + l];
        }
        const u16* ab = As + lc * STRIDE + kt * 32 + lk * 8;
        __builtin_amdgcn_s_setprio(1);
        #pragma unroll
        for (int m = 0; m < 4; ++m) {
            short8v a = *(const short8v*)(ab + m * (16 * STRIDE));
            #pragma unroll
            for (int n = 0; n < 5; ++n)
                acc[m][n] = __builtin_amdgcn_mfma_f32_16x16x32_bf16(a, bb[kt & 1][n], acc[m][n], 0, 0, 0);
        }
        __builtin_amdgcn_s_setprio(0);
    }
    __syncthreads();   // all x-tile reads done; safe to overwrite As with h

    // ---- bias + relu, then h (bf16) in place over As ----
    #pragma unroll
    for (int n = 0; n < 5; ++n) {
        float bn = B1[w * 80 + n * 16 + lc];
        #pragma unroll
        for (int m = 0; m < 4; ++m) {
            #pragma unroll
            for (int j = 0; j < 4; ++j) {
                float hv = fmaxf(acc[m][n][j] + bn, 0.0f);
                As[(m * 16 + lk * 4 + j) * STRIDE + (w * 80 + n * 16 + lc)] = f2bf(hv);
            }
        }
    }
    __syncthreads();   // h complete

    // ---- GEMM2: logits partials via MFMA; wave w covers its kt slice ----
    // waves 0..4 -> 3 kts, waves 5..9 -> 2 kts (25 total)
    {
        const int ks  = (w < 5) ? 3 * w : 15 + 2 * (w - 5);
        const int cnt = (w < 5) ? 3 : 2;
        const short8v* WP = (const short8v*)W4P;
        f32x4 pc[4];
        #pragma unroll
        for (int m = 0; m < 4; ++m) pc[m] = (f32x4)(0.0f);
        #pragma unroll
        for (int i = 0; i < 3; ++i) {
            if (i < cnt) {
                int kt = ks + i;
                short8v b = WP[kt * 64 + l];
                #pragma unroll
                for (int m = 0; m < 4; ++m) {
                    short8v a = *(const short8v*)(As + (m * 16 + lc) * STRIDE + kt * 32 + lk * 8);
                    pc[m] = __builtin_amdgcn_mfma_f32_16x16x32_bf16(a, b, pc[m], 0, 0, 0);
                }
            }
        }
        f32x4* PLv = (f32x4*)PL2;
        #pragma unroll
        for (int m = 0; m < 4; ++m)
            PLv[(w * 4 + m) * 64 + l] = pc[m];
    }
    __syncthreads();

    // ---- combine partials + bias + log_softmax, one row per thread ----
    if (t < 64) {
        const int r = t;
        const int m = r >> 4, sub = ((r & 15) >> 2) * 16, j = r & 3;
        float lg[10];
        #pragma unroll
        for (int o = 0; o < 10; ++o) {
            float s = B4[o];
            #pragma unroll
            for (int w2 = 0; w2 < 10; ++w2)
                s += PL2[(((w2 * 4 + m) * 64) + sub + o) * 4 + j];
            lg[o] = s;
        }
        float mx = lg[0];
        #pragma unroll
        for (int o = 1; o < 10; ++o) mx = fmaxf(mx, lg[o]);
        float se = 0.f;
        #pragma unroll
        for (int o = 0; o < 10; ++o) se += expf(lg[o] - mx);
        float lse = logf(se);
        float* op = OUT + (size_t)(row0 + r) * 10;
        #pragma unroll
        for (int o = 0; o < 10; ++o) op[o] = lg[o] - mx - lse;
    }
}

// ---------------------------------------------------------------------------
extern "C" void kernel_launch(void* const* d_in, const int* in_sizes, int n_in,
                              void* d_out, int out_size, void* d_ws, size_t ws_size,
                              hipStream_t stream)
{
    const float* X   = (const float*)d_in[0];
    const float* MRE = (const float*)d_in[1];
    const float* MIM = (const float*)d_in[2];
    const float* W1  = (const float*)d_in[3];
    const float* B1  = (const float*)d_in[4];
    const float* W4  = (const float*)d_in[5];
    const float* B4  = (const float*)d_in[6];
    float* OUT = (float*)d_out;

    float* kre  = (float*)d_ws;                       // 784 f32
    float* flag = kre + 784;                          // 1 f32
    u16*   w1p  = (u16*)((char*)d_ws + 4096);         // 800*25*64*8... = 1.28 MB
    u16*   w4p  = (u16*)((char*)d_ws + 4096 + 1310720); // 25*64*8 u16 = 25.6 KB

    k_kre<<<1, 832, 0, stream>>>(MRE, MIM, kre, flag);
    k_w1pack<<<800, 128, 0, stream>>>(W1, kre, flag, w1p);
    k_w4pack<<<7, 256, 0, stream>>>(W4, w4p);
    k_main<<<512, 640, 0, stream>>>(X, w1p, w4p, B1, B4, OUT);
}